// Round 5
// baseline (20.316 us; speedup 1.0000x reference)
//
#include <hip/hip_runtime.h>
#include <hip/hip_bf16.h>

// Fully-fused quantum photonic classifier.
// Permanent core: scalar Glynn/BBF (16 Gray-coded sign vectors), one permanent
// per thread, A resident in registers (gathered from LDS), tree-structured
// 5-term product (depth 3). 256 blocks x 1024 threads: 4 waves/SIMD for
// latency hiding (the R4 pair-packed version held 100 VGPRs of A and capped
// occupancy at 2 waves/SIMD -> latency-bound).

__device__ __forceinline__ float2 cxmul(float2 a, float2 b) {
    float2 r;
    r.x = fmaf(a.x, b.x, -(a.y * b.y));
    r.y = fmaf(a.x, b.y, a.y * b.x);
    return r;
}

// tree product of the 5 row sums: ((r0*r1)*(r2*r3))*r4, depth 3
__device__ __forceinline__ float2 prod5t(const float2 (&rs)[5]) {
    float2 t01 = cxmul(rs[0], rs[1]);
    float2 t23 = cxmul(rs[2], rs[3]);
    float2 t = cxmul(t01, t23);
    return cxmul(t, rs[4]);
}

// Glynn step K (K = 1..15): toggle sign of column j = ctz(K)+1, update row
// sums by +-2*A[r][j], multiply rows, accumulate with parity sign.
template<int K>
__device__ __forceinline__ void glynn_step(const float2 (&A)[5][5], float2 (&rs)[5], float2& pm) {
    constexpr unsigned g    = (unsigned)K ^ ((unsigned)K >> 1);
    constexpr unsigned og   = (unsigned)(K - 1) ^ ((unsigned)(K - 1) >> 1);
    constexpr unsigned diff = g ^ og;
    constexpr int b = (diff & 1u) ? 0 : (diff & 2u) ? 1 : (diff & 4u) ? 2 : 3;
    constexpr int j = b + 1;                       // columns 1..4 toggle
    constexpr float s2 = ((g & diff) != 0u) ? -2.0f : 2.0f;
#pragma unroll
    for (int r = 0; r < 5; ++r) {
        rs[r].x = fmaf(s2, A[r][j].x, rs[r].x);
        rs[r].y = fmaf(s2, A[r][j].y, rs[r].y);
    }
    float2 z = prod5t(rs);
    constexpr int pc = ((g >> 0) & 1) + ((g >> 1) & 1) + ((g >> 2) & 1) + ((g >> 3) & 1);
    if constexpr (pc & 1) { pm.x -= z.x; pm.y -= z.y; }
    else                  { pm.x += z.x; pm.y += z.y; }
}

template<int K>
__device__ __forceinline__ void glynn_rest(const float2 (&A)[5][5], float2 (&rs)[5], float2& pm) {
    glynn_step<K>(A, rs, pm);
    if constexpr (K < 15) glynn_rest<K + 1>(A, rs, pm);
}

// 256 * |perm(A)|^2 where rows of A are modes packed 4-bit in `mp`,
// columns from Bsh (10 modes x 5 cols, AoS complex float2).
__device__ __forceinline__ float glynn_sq(const float2* __restrict__ Bsh, unsigned mp) {
    float2 A[5][5];
#pragma unroll
    for (int r = 0; r < 5; ++r) {
        const float2* br = Bsh + ((mp >> (4 * r)) & 15u) * 5;
#pragma unroll
        for (int c = 0; c < 5; ++c) A[r][c] = br[c];
    }
    float2 rs[5];
#pragma unroll
    for (int r = 0; r < 5; ++r) {
        float2 s01, s23;
        s01.x = A[r][0].x + A[r][1].x; s01.y = A[r][0].y + A[r][1].y;
        s23.x = A[r][2].x + A[r][3].x; s23.y = A[r][2].y + A[r][3].y;
        rs[r].x = s01.x + s23.x + A[r][4].x;
        rs[r].y = s01.y + s23.y + A[r][4].y;
    }
    float2 pm = prod5t(rs);                        // g = 0, sign +
    glynn_rest<1>(A, rs, pm);
    return fmaf(pm.x, pm.x, pm.y * pm.y);          // = 256 * |perm|^2
}

__device__ __forceinline__ unsigned pack_rows(const int* __restrict__ r) {
    return (unsigned)r[0] | ((unsigned)r[1] << 4) | ((unsigned)r[2] << 8)
         | ((unsigned)r[3] << 12) | ((unsigned)r[4] << 16);
}

__global__ __launch_bounds__(1024) void k_fused(
    const float* __restrict__ x, const float* __restrict__ Wd, const float* __restrict__ bd,
    const float* __restrict__ U1L, const float* __restrict__ U1R,
    const float* __restrict__ UfL, const float* __restrict__ UfR,
    const float* __restrict__ Wout, const float* __restrict__ bout,
    const float* __restrict__ mask1, const float* __restrict__ norm2,
    const int* __restrict__ rows1, const int* __restrict__ rows2,
    float* __restrict__ out)
{
    const int n    = blockIdx.x;
    const int tid  = threadIdx.x;
    const int lane = tid & 63;
    const int wid  = tid >> 6;   // 16 waves

    __shared__ float2 Bsh[50];        // B1 then B2 (10 modes x 5 cols)
    __shared__ float  p1s[256];
    __shared__ float2 Dsh[10];
    __shared__ float  sred[10][16];
    __shared__ float  epart[32][10];
    __shared__ float  tred[4];
    __shared__ float  fred[16][2];

    // ---- phase 1: h = x[n] @ Wd^T + bd -> D1 = exp(i h/pi) --------------
    float acc[10];
#pragma unroll
    for (int j = 0; j < 10; ++j) acc[j] = 0.f;
    const float* xr = x + n * 784;
    if (tid < 784) {
        float xv = xr[tid];
#pragma unroll
        for (int j = 0; j < 10; ++j) acc[j] = fmaf(xv, Wd[j * 784 + tid], acc[j]);
    }
#pragma unroll
    for (int off = 32; off > 0; off >>= 1)
#pragma unroll
        for (int j = 0; j < 10; ++j) acc[j] += __shfl_xor(acc[j], off, 64);
    if (lane == 0)
#pragma unroll
        for (int j = 0; j < 10; ++j) sred[j][wid] = acc[j];
    __syncthreads();
    if (tid < 10) {
        float h = bd[tid];
#pragma unroll
        for (int w = 0; w < 16; ++w) h += sred[tid][w];
        float s, c;
        sincosf(h * 0.31830988618379067154f, &s, &c);   // h / pi
        Dsh[tid] = make_float2(c, s);
    }
    __syncthreads();
    // B1 = U1L diag(D1) U1R[:, even]
    if (tid < 50) {
        const int i = tid / 5, k = 2 * (tid % 5);
        float2 a = make_float2(0.f, 0.f);
#pragma unroll
        for (int j = 0; j < 10; ++j) {
            float2 ul = make_float2(U1L[(i * 10 + j) * 2], U1L[(i * 10 + j) * 2 + 1]);
            float2 ur = make_float2(U1R[(j * 10 + k) * 2], U1R[(j * 10 + k) * 2 + 1]);
            float2 t = cxmul(cxmul(ul, Dsh[j]), ur);
            a.x += t.x; a.y += t.y;
        }
        Bsh[tid] = a;
    }
    __syncthreads();

    // ---- phase 2: circuit-1 permanents (252) -> e1 -> D2 -> B2 ----------
    // Glynn's 1/256 scale cancels in the p1/total normalization.
    if (tid < 252) {
        p1s[tid] = glynn_sq(Bsh, pack_rows(rows1 + tid * 5));
    } else if (tid < 256) {
        p1s[tid] = 0.f;
    }
    __syncthreads();
    if (tid < 256) {
        float vv = p1s[tid];
#pragma unroll
        for (int off = 32; off > 0; off >>= 1) vv += __shfl_xor(vv, off, 64);
        if (lane == 0) tred[wid] = vv;
    }
    if (tid < 320) {
        const int c = tid / 10, j = tid - c * 10;
        float s = 0.f;
        const int p0 = c * 8, p1e = (p0 + 8 < 252) ? p0 + 8 : 252;
        for (int p = p0; p < p1e; ++p) s = fmaf(p1s[p], mask1[p * 10 + j], s);
        epart[c][j] = s;
    }
    __syncthreads();
    if (tid < 10) {
        const float total = tred[0] + tred[1] + tred[2] + tred[3];
        float e = 0.f;
#pragma unroll
        for (int c = 0; c < 32; ++c) e += epart[c][tid];
        e /= total;
        float s, cc;
        sincosf(e, &s, &cc);
        Dsh[tid] = make_float2(cc, s);
    }
    __syncthreads();
    if (tid < 50) {
        const int i = tid / 5, k = 2 * (tid % 5);
        float2 a = make_float2(0.f, 0.f);
#pragma unroll
        for (int j = 0; j < 10; ++j) {
            float2 ul = make_float2(UfL[(i * 10 + j) * 2], UfL[(i * 10 + j) * 2 + 1]);
            float2 ur = make_float2(UfR[(j * 10 + k) * 2], UfR[(j * 10 + k) * 2 + 1]);
            float2 t = cxmul(cxmul(ul, Dsh[j]), ur);
            a.x += t.x; a.y += t.y;
        }
        Bsh[tid] = a;   // overwrite with B2 (all B1 consumers done)
    }
    __syncthreads();

    // ---- phase 3: circuit-2 permanents (2002) + W_out dot ---------------
    float f0 = 0.f, f1 = 0.f;
#pragma unroll 1
    for (int p = tid; p < 2002; p += 1024) {
        const float sq = glynn_sq(Bsh, pack_rows(rows2 + p * 5));
        const float pf = sq * norm2[p] * 0.00390625f;   // 1/256 Glynn scale
        f0 = fmaf(pf, Wout[p], f0);
        f1 = fmaf(pf, Wout[2002 + p], f1);
    }
#pragma unroll
    for (int off = 32; off > 0; off >>= 1) {
        f0 += __shfl_xor(f0, off, 64);
        f1 += __shfl_xor(f1, off, 64);
    }
    if (lane == 0) { fred[wid][0] = f0; fred[wid][1] = f1; }
    __syncthreads();
    if (tid < 2) {
        float a = bout[tid];
#pragma unroll
        for (int w = 0; w < 16; ++w) a += fred[w][tid];
        out[n * 2 + tid] = a;
    }
}

extern "C" void kernel_launch(void* const* d_in, const int* in_sizes, int n_in,
                              void* d_out, int out_size, void* d_ws, size_t ws_size,
                              hipStream_t stream) {
    const float* x     = (const float*)d_in[0];
    const float* Wd    = (const float*)d_in[1];
    const float* bd    = (const float*)d_in[2];
    const float* U1L   = (const float*)d_in[3];
    const float* U1R   = (const float*)d_in[4];
    const float* UfL   = (const float*)d_in[5];
    const float* UfR   = (const float*)d_in[6];
    const float* Wout  = (const float*)d_in[7];
    const float* bout  = (const float*)d_in[8];
    const float* mask1 = (const float*)d_in[9];
    const float* norm2 = (const float*)d_in[10];
    const int*   rows1 = (const int*)d_in[11];
    const int*   rows2 = (const int*)d_in[12];
    float* out = (float*)d_out;

    hipLaunchKernelGGL(k_fused, dim3(256), dim3(1024), 0, stream,
                       x, Wd, bd, U1L, U1R, UfL, UfR, Wout, bout,
                       mask1, norm2, rows1, rows2, out);
}

// Round 6
// 19.105 us; speedup vs baseline: 1.0634x; 1.0634x over previous
//
#include <hip/hip_runtime.h>
#include <hip/hip_bf16.h>

// Fully-fused quantum photonic classifier via polynomial-coefficient DP.
// perm(B[rows mu]) / prod(mu!) = coeff of x^mu in prod_c (sum_m x_m B[m][c]).
// One block per sample (256 x 1024). DP stages over multiset degrees
// 1(10) -> 2(55) -> 3(220) -> 4(715) -> 5(2002); each output gathers <=d
// parents. Parent indices = colex multiset ranks, built once into registers
// (data-independent), reused for both circuits. ~11K complex fma per circuit
// vs ~1.1M scalar flops for per-permanent Glynn.

__device__ __forceinline__ float2 cxmul(float2 a, float2 b) {
    float2 r;
    r.x = fmaf(a.x, b.x, -(a.y * b.y));
    r.y = fmaf(a.x, b.y, a.y * b.x);
    return r;
}

// colex unrank of a degree-D multiset over modes 0..9 (lex = cwr order NOT
// needed here; any bijection works for intermediate stages).
// rank = sum_i C(m_i + i, i+1), m sorted ascending.
template<int D>
__device__ __forceinline__ void unrank_ms(int R, const int* bn, int (&m)[D]) {
    int hi = 9 + D - 1;
#pragma unroll
    for (int i = D - 1; i >= 0; --i) {
        int c = hi;
        while (bn[c * 6 + (i + 1)] > R) --c;   // terminates: C(i,i+1)=0<=R
        R -= bn[c * 6 + (i + 1)];
        m[i] = c - i;
        hi = c - 1;
    }
}

// For sorted multiset m[0..D-1], edge j = (colex rank of multiset minus
// m[j], mode m[j]), valid only at first occurrence of each distinct value.
// parent_rank(j) = P_j + S_j with P/S prefix/suffix binomial sums.
template<int D>
__device__ __forceinline__ void build_edges(const int (&m)[D], const int* bn, unsigned (&e)[D]) {
    int c[D];
#pragma unroll
    for (int i = 0; i < D; ++i) c[i] = m[i] + i;
    int P[D];
    P[0] = 0;
#pragma unroll
    for (int j = 1; j < D; ++j) P[j] = P[j - 1] + bn[c[j - 1] * 6 + j];
    int S[D];
    S[D - 1] = 0;
#pragma unroll
    for (int j = D - 2; j >= 0; --j) S[j] = S[j + 1] + bn[(c[j + 1] - 1) * 6 + (j + 1)];
#pragma unroll
    for (int j = 0; j < D; ++j) {
        bool valid = (j == 0) || (m[j] != m[j - 1]);
        unsigned edge = (((unsigned)(P[j] + S[j])) << 4) | (unsigned)m[j] | 0x80000000u;
        e[j] = valid ? edge : 0u;
    }
}

// acc += B[mode][col] * parent_coeff   (complex, 4 fma)
__device__ __forceinline__ float2 dp_acc(float2 acc, unsigned e, const float2* pbuf,
                                         const float2* B, int col) {
    if (e & 0x80000000u) {
        float2 p = pbuf[(e >> 4) & 0x3FFu];
        float2 b = B[(e & 15u) * 5 + col];
        acc.x = fmaf(b.x, p.x, acc.x);
        acc.x = fmaf(-b.y, p.y, acc.x);
        acc.y = fmaf(b.x, p.y, acc.y);
        acc.y = fmaf(b.y, p.x, acc.y);
    }
    return acc;
}

__global__ __launch_bounds__(1024) void k_fused(
    const float* __restrict__ x, const float* __restrict__ Wd, const float* __restrict__ bd,
    const float* __restrict__ U1L, const float* __restrict__ U1R,
    const float* __restrict__ UfL, const float* __restrict__ UfR,
    const float* __restrict__ Wout, const float* __restrict__ bout,
    const float* __restrict__ mask1, const float* __restrict__ norm2,
    const int* __restrict__ rows1, const int* __restrict__ rows2,
    float* __restrict__ out)
{
    const int n    = blockIdx.x;
    const int tid  = threadIdx.x;
    const int lane = tid & 63;
    const int wid  = tid >> 6;   // 16 waves

    __shared__ int    binom[90];      // C(n,k), n<15, k<6
    __shared__ float2 Bsh[50];        // current circuit matrix (10 modes x 5 cols)
    __shared__ float2 buf1[220];      // DP stages 1,3
    __shared__ float2 buf2[715];      // DP stages 2,4
    __shared__ float  p1s[256];
    __shared__ float2 Dsh[10];
    __shared__ float  sred[10][16];
    __shared__ float  epart[32][10];
    __shared__ float  tred[4];
    __shared__ float  fred[16][2];

    // ---- issue data-loads early (latency hides under edge build) --------
    float xv = 0.f;
    float wv[10];
#pragma unroll
    for (int j = 0; j < 10; ++j) wv[j] = 0.f;
    if (tid < 784) {
        xv = x[n * 784 + tid];
#pragma unroll
        for (int j = 0; j < 10; ++j) wv[j] = Wd[j * 784 + tid];
    }
    int m5a[5];
#pragma unroll
    for (int j = 0; j < 5; ++j) m5a[j] = 0;
    if (tid < 252) {
#pragma unroll
        for (int j = 0; j < 5; ++j) m5a[j] = rows1[tid * 5 + j];
    }
    int m5b0[5];                       // p0 = tid (always < 2002)
#pragma unroll
    for (int j = 0; j < 5; ++j) m5b0[j] = rows2[tid * 5 + j];
    int m5b1[5];                       // p1 = tid + 1024 (if < 2002)
#pragma unroll
    for (int j = 0; j < 5; ++j) m5b1[j] = 0;
    const bool has_p1 = (tid + 1024) < 2002;
    if (has_p1) {
#pragma unroll
        for (int j = 0; j < 5; ++j) m5b1[j] = rows2[(tid + 1024) * 5 + j];
    }

    // ---- binomial table -------------------------------------------------
    if (tid < 90) {
        const int nn = tid / 6, kk = tid - (tid / 6) * 6;
        int r = (kk <= nn) ? 1 : 0;
        for (int i = 1; i <= kk && r; ++i) r = r * (nn - kk + i) / i;
        binom[tid] = r;
    }
    __syncthreads();

    // ---- build DP edges (data-independent, kept in registers) -----------
    unsigned e2[2], e3[3], e4[4], e5a[5], e5b0[5], e5b1[5];
#pragma unroll
    for (int j = 0; j < 2; ++j) e2[j] = 0u;
#pragma unroll
    for (int j = 0; j < 3; ++j) e3[j] = 0u;
#pragma unroll
    for (int j = 0; j < 4; ++j) e4[j] = 0u;
#pragma unroll
    for (int j = 0; j < 5; ++j) { e5a[j] = 0u; e5b1[j] = 0u; }
    if (tid < 55)  { int m[2]; unrank_ms<2>(tid, binom, m); build_edges<2>(m, binom, e2); }
    if (tid < 220) { int m[3]; unrank_ms<3>(tid, binom, m); build_edges<3>(m, binom, e3); }
    if (tid < 715) { int m[4]; unrank_ms<4>(tid, binom, m); build_edges<4>(m, binom, e4); }
    if (tid < 252) { build_edges<5>(m5a, binom, e5a); }
    build_edges<5>(m5b0, binom, e5b0);
    if (has_p1) { build_edges<5>(m5b1, binom, e5b1); }
    // multiplicity factorial prod(mu!) for final outputs
    float fact0, fact1;
    {
        int f = 1, c = 1;
#pragma unroll
        for (int j = 1; j < 5; ++j) { c = (m5b0[j] == m5b0[j - 1]) ? c + 1 : 1; f *= c; }
        fact0 = (float)f;
        f = 1; c = 1;
#pragma unroll
        for (int j = 1; j < 5; ++j) { c = (m5b1[j] == m5b1[j - 1]) ? c + 1 : 1; f *= c; }
        fact1 = (float)f;
    }

    // ---- phase 1: h = x[n] @ Wd^T + bd -> D1 = exp(i h / pi) ------------
    float acc[10];
#pragma unroll
    for (int j = 0; j < 10; ++j) acc[j] = xv * wv[j];
#pragma unroll
    for (int off = 32; off > 0; off >>= 1)
#pragma unroll
        for (int j = 0; j < 10; ++j) acc[j] += __shfl_xor(acc[j], off, 64);
    if (lane == 0)
#pragma unroll
        for (int j = 0; j < 10; ++j) sred[j][wid] = acc[j];
    __syncthreads();
    if (tid < 10) {
        float h = bd[tid];
#pragma unroll
        for (int w = 0; w < 16; ++w) h += sred[tid][w];
        float s, c;
        sincosf(h * 0.31830988618379067154f, &s, &c);
        Dsh[tid] = make_float2(c, s);
    }
    __syncthreads();
    // B1 = U1L diag(D1) U1R[:, even]; col-0 threads also seed DP stage 1
    if (tid < 50) {
        const int i = tid / 5, cc = tid % 5, k = 2 * cc;
        float2 a = make_float2(0.f, 0.f);
#pragma unroll
        for (int j = 0; j < 10; ++j) {
            float2 ul = make_float2(U1L[(i * 10 + j) * 2], U1L[(i * 10 + j) * 2 + 1]);
            float2 ur = make_float2(U1R[(j * 10 + k) * 2], U1R[(j * 10 + k) * 2 + 1]);
            float2 t = cxmul(cxmul(ul, Dsh[j]), ur);
            a.x += t.x; a.y += t.y;
        }
        Bsh[tid] = a;
        if (cc == 0) buf1[i] = a;      // stage-1 coeffs = B[:,0]
    }
    __syncthreads();

    // ---- circuit-1 DP ---------------------------------------------------
    if (tid < 55) {
        float2 a = make_float2(0.f, 0.f);
#pragma unroll
        for (int j = 0; j < 2; ++j) a = dp_acc(a, e2[j], buf1, Bsh, 1);
        buf2[tid] = a;
    }
    __syncthreads();
    if (tid < 220) {
        float2 a = make_float2(0.f, 0.f);
#pragma unroll
        for (int j = 0; j < 3; ++j) a = dp_acc(a, e3[j], buf2, Bsh, 2);
        buf1[tid] = a;
    }
    __syncthreads();
    if (tid < 715) {
        float2 a = make_float2(0.f, 0.f);
#pragma unroll
        for (int j = 0; j < 4; ++j) a = dp_acc(a, e4[j], buf1, Bsh, 3);
        buf2[tid] = a;
    }
    __syncthreads();
    if (tid < 252) {
        float2 a = make_float2(0.f, 0.f);
#pragma unroll
        for (int j = 0; j < 5; ++j) a = dp_acc(a, e5a[j], buf2, Bsh, 4);
        p1s[tid] = fmaf(a.x, a.x, a.y * a.y);   // squarefree: prod(mu!) = 1
    } else if (tid < 256) {
        p1s[tid] = 0.f;
    }
    __syncthreads();

    // ---- e1 = (p1/sum) @ mask1 -> D2 -> B2 ------------------------------
    if (tid < 256) {
        float vv = p1s[tid];
#pragma unroll
        for (int off = 32; off > 0; off >>= 1) vv += __shfl_xor(vv, off, 64);
        if (lane == 0) tred[wid] = vv;
    }
    if (tid < 320) {
        const int c = tid / 10, j = tid - c * 10;
        float s = 0.f;
        const int p0 = c * 8, p1e = (p0 + 8 < 252) ? p0 + 8 : 252;
        for (int p = p0; p < p1e; ++p) s = fmaf(p1s[p], mask1[p * 10 + j], s);
        epart[c][j] = s;
    }
    __syncthreads();
    if (tid < 10) {
        const float total = tred[0] + tred[1] + tred[2] + tred[3];
        float e = 0.f;
#pragma unroll
        for (int c = 0; c < 32; ++c) e += epart[c][tid];
        e /= total;
        float s, cc;
        sincosf(e, &s, &cc);
        Dsh[tid] = make_float2(cc, s);
    }
    __syncthreads();
    if (tid < 50) {
        const int i = tid / 5, cc = tid % 5, k = 2 * cc;
        float2 a = make_float2(0.f, 0.f);
#pragma unroll
        for (int j = 0; j < 10; ++j) {
            float2 ul = make_float2(UfL[(i * 10 + j) * 2], UfL[(i * 10 + j) * 2 + 1]);
            float2 ur = make_float2(UfR[(j * 10 + k) * 2], UfR[(j * 10 + k) * 2 + 1]);
            float2 t = cxmul(cxmul(ul, Dsh[j]), ur);
            a.x += t.x; a.y += t.y;
        }
        Bsh[tid] = a;
        if (cc == 0) buf1[i] = a;
    }
    __syncthreads();

    // ---- circuit-2 DP (same edges) --------------------------------------
    if (tid < 55) {
        float2 a = make_float2(0.f, 0.f);
#pragma unroll
        for (int j = 0; j < 2; ++j) a = dp_acc(a, e2[j], buf1, Bsh, 1);
        buf2[tid] = a;
    }
    __syncthreads();
    if (tid < 220) {
        float2 a = make_float2(0.f, 0.f);
#pragma unroll
        for (int j = 0; j < 3; ++j) a = dp_acc(a, e3[j], buf2, Bsh, 2);
        buf1[tid] = a;
    }
    __syncthreads();
    if (tid < 715) {
        float2 a = make_float2(0.f, 0.f);
#pragma unroll
        for (int j = 0; j < 4; ++j) a = dp_acc(a, e4[j], buf1, Bsh, 3);
        buf2[tid] = a;
    }
    __syncthreads();
    float f0 = 0.f, f1 = 0.f;
    {
        float2 a = make_float2(0.f, 0.f);
#pragma unroll
        for (int j = 0; j < 5; ++j) a = dp_acc(a, e5b0[j], buf2, Bsh, 4);
        const float pf = fmaf(a.x, a.x, a.y * a.y) * fact0;   // |coeff|^2 * prod(mu!)
        f0 = fmaf(pf, Wout[tid], f0);
        f1 = fmaf(pf, Wout[2002 + tid], f1);
    }
    if (has_p1) {
        float2 a = make_float2(0.f, 0.f);
#pragma unroll
        for (int j = 0; j < 5; ++j) a = dp_acc(a, e5b1[j], buf2, Bsh, 4);
        const float pf = fmaf(a.x, a.x, a.y * a.y) * fact1;
        f0 = fmaf(pf, Wout[tid + 1024], f0);
        f1 = fmaf(pf, Wout[2002 + tid + 1024], f1);
    }
#pragma unroll
    for (int off = 32; off > 0; off >>= 1) {
        f0 += __shfl_xor(f0, off, 64);
        f1 += __shfl_xor(f1, off, 64);
    }
    if (lane == 0) { fred[wid][0] = f0; fred[wid][1] = f1; }
    __syncthreads();
    if (tid < 2) {
        float a = bout[tid];
#pragma unroll
        for (int w = 0; w < 16; ++w) a += fred[w][tid];
        out[n * 2 + tid] = a;
    }
}

extern "C" void kernel_launch(void* const* d_in, const int* in_sizes, int n_in,
                              void* d_out, int out_size, void* d_ws, size_t ws_size,
                              hipStream_t stream) {
    const float* x     = (const float*)d_in[0];
    const float* Wd    = (const float*)d_in[1];
    const float* bd    = (const float*)d_in[2];
    const float* U1L   = (const float*)d_in[3];
    const float* U1R   = (const float*)d_in[4];
    const float* UfL   = (const float*)d_in[5];
    const float* UfR   = (const float*)d_in[6];
    const float* Wout  = (const float*)d_in[7];
    const float* bout  = (const float*)d_in[8];
    const float* mask1 = (const float*)d_in[9];
    const float* norm2 = (const float*)d_in[10];
    const int*   rows1 = (const int*)d_in[11];
    const int*   rows2 = (const int*)d_in[12];
    float* out = (float*)d_out;

    hipLaunchKernelGGL(k_fused, dim3(256), dim3(1024), 0, stream,
                       x, Wd, bd, U1L, U1R, UfL, UfR, Wout, bout,
                       mask1, norm2, rows1, rows2, out);
}

// Round 7
// 16.839 us; speedup vs baseline: 1.2065x; 1.1346x over previous
//
#include <hip/hip_runtime.h>
#include <hip/hip_bf16.h>

// Fully-fused quantum photonic classifier via polynomial-coefficient DP.
// perm(B[rows mu]) / prod(mu!) = coeff of x^mu in prod_c (sum_m x_m B[m][c]).
// One block per sample (256 x 1024). DP stages over multiset degrees
// 1(10) -> 2(55) -> 3(220) -> 4(715) -> 5(2002).
// R7 change vs R6: ALL index math (unrank + edge ranks) is branchless
// closed-form VALU -- the R6 version's serial LDS binom-table probe chains
// (~10K latency cycles/thread) were the bottleneck, not the DP math.

__device__ __forceinline__ float2 cxmul(float2 a, float2 b) {
    float2 r;
    r.x = fmaf(a.x, b.x, -(a.y * b.y));
    r.y = fmaf(a.x, b.y, a.y * b.x);
    return r;
}

// exact C(c,k) for 0 <= c <= 14, 0 <= k <= 5. Products auto-zero for c < k.
// k is always an unroll-constant -> compiler folds the switch + magic divs.
__device__ __forceinline__ int Crt(int c, int k) {
    switch (k) {
        case 0:  return 1;
        case 1:  return c;
        case 2:  return (int)((unsigned)(c * (c - 1)) >> 1);
        case 3:  return (int)((unsigned)(c * (c - 1) * (c - 2)) / 6u);
        case 4:  return (int)((unsigned)(c * (c - 1) * (c - 2) * (c - 3)) / 24u);
        default: return (int)((unsigned)(c * (c - 1) * (c - 2) * (c - 3) * (c - 4)) / 120u);
    }
}

// colex unrank of a degree-D multiset over modes 0..9.
// digit i = largest c in [i, i+9] with C(c, i+1) <= R, via branchless count.
template<int D>
__device__ __forceinline__ void unrank_ms(int R, int (&m)[D]) {
#pragma unroll
    for (int i = D - 1; i >= 0; --i) {
        int c = i;
#pragma unroll
        for (int v = 1; v <= 9; ++v)
            c += (Crt(i + v, i + 1) <= R) ? 1 : 0;
        R -= Crt(c, i + 1);
        m[i] = c - i;
    }
}

// For sorted multiset m[0..D-1], edge j = (rank of multiset minus m[j],
// mode m[j]), valid only at first occurrence of each distinct value.
template<int D>
__device__ __forceinline__ void build_edges(const int (&m)[D], unsigned (&e)[D]) {
    int c[D];
#pragma unroll
    for (int i = 0; i < D; ++i) c[i] = m[i] + i;
    int P[D];
    P[0] = 0;
#pragma unroll
    for (int j = 1; j < D; ++j) P[j] = P[j - 1] + Crt(c[j - 1], j);
    int S[D];
    S[D - 1] = 0;
#pragma unroll
    for (int j = D - 2; j >= 0; --j) S[j] = S[j + 1] + Crt(c[j + 1] - 1, j + 1);
#pragma unroll
    for (int j = 0; j < D; ++j) {
        bool valid = (j == 0) || (m[j] != m[j - 1]);
        unsigned edge = (((unsigned)(P[j] + S[j])) << 4) | (unsigned)m[j] | 0x80000000u;
        e[j] = valid ? edge : 0u;
    }
}

// acc += B[mode][col] * parent_coeff   (complex, 4 fma)
__device__ __forceinline__ float2 dp_acc(float2 acc, unsigned e, const float2* pbuf,
                                         const float2* B, int col) {
    if (e & 0x80000000u) {
        float2 p = pbuf[(e >> 4) & 0x3FFu];
        float2 b = B[(e & 15u) * 5 + col];
        acc.x = fmaf(b.x, p.x, acc.x);
        acc.x = fmaf(-b.y, p.y, acc.x);
        acc.y = fmaf(b.x, p.y, acc.y);
        acc.y = fmaf(b.y, p.x, acc.y);
    }
    return acc;
}

__global__ __launch_bounds__(1024) void k_fused(
    const float* __restrict__ x, const float* __restrict__ Wd, const float* __restrict__ bd,
    const float* __restrict__ U1L, const float* __restrict__ U1R,
    const float* __restrict__ UfL, const float* __restrict__ UfR,
    const float* __restrict__ Wout, const float* __restrict__ bout,
    const float* __restrict__ mask1, const float* __restrict__ norm2,
    const int* __restrict__ rows1, const int* __restrict__ rows2,
    float* __restrict__ out)
{
    const int n    = blockIdx.x;
    const int tid  = threadIdx.x;
    const int lane = tid & 63;
    const int wid  = tid >> 6;   // 16 waves

    __shared__ float2 Bsh[50];        // current circuit matrix (10 modes x 5 cols)
    __shared__ float2 buf1[220];      // DP stages 1,3
    __shared__ float2 buf2[715];      // DP stages 2,4
    __shared__ float  p1s[256];
    __shared__ float2 Dsh[10];
    __shared__ float  sred[10][16];
    __shared__ float  epart[32][10];
    __shared__ float  tred[4];
    __shared__ float  fred[16][2];

    // ---- issue data-loads early (latency hides under edge build) --------
    float xv = 0.f;
    float wv[10];
#pragma unroll
    for (int j = 0; j < 10; ++j) wv[j] = 0.f;
    if (tid < 784) {
        xv = x[n * 784 + tid];
#pragma unroll
        for (int j = 0; j < 10; ++j) wv[j] = Wd[j * 784 + tid];
    }
    int m5a[5];
#pragma unroll
    for (int j = 0; j < 5; ++j) m5a[j] = 0;
    if (tid < 252) {
#pragma unroll
        for (int j = 0; j < 5; ++j) m5a[j] = rows1[tid * 5 + j];
    }
    int m5b0[5];                       // p0 = tid (always < 2002)
#pragma unroll
    for (int j = 0; j < 5; ++j) m5b0[j] = rows2[tid * 5 + j];
    int m5b1[5];                       // p1 = tid + 1024 (if < 2002)
#pragma unroll
    for (int j = 0; j < 5; ++j) m5b1[j] = 0;
    const bool has_p1 = (tid + 1024) < 2002;
    if (has_p1) {
#pragma unroll
        for (int j = 0; j < 5; ++j) m5b1[j] = rows2[(tid + 1024) * 5 + j];
    }

    // ---- build DP edges (data-independent, branchless VALU, no LDS) -----
    unsigned e2[2], e3[3], e4[4], e5a[5], e5b0[5], e5b1[5];
#pragma unroll
    for (int j = 0; j < 2; ++j) e2[j] = 0u;
#pragma unroll
    for (int j = 0; j < 3; ++j) e3[j] = 0u;
#pragma unroll
    for (int j = 0; j < 4; ++j) e4[j] = 0u;
#pragma unroll
    for (int j = 0; j < 5; ++j) { e5a[j] = 0u; e5b1[j] = 0u; }
    if (tid < 55)  { int m[2]; unrank_ms<2>(tid, m); build_edges<2>(m, e2); }
    if (tid < 220) { int m[3]; unrank_ms<3>(tid, m); build_edges<3>(m, e3); }
    if (tid < 715) { int m[4]; unrank_ms<4>(tid, m); build_edges<4>(m, e4); }
    if (tid < 252) { build_edges<5>(m5a, e5a); }
    build_edges<5>(m5b0, e5b0);
    if (has_p1) { build_edges<5>(m5b1, e5b1); }
    // multiplicity factorial prod(mu!) for final outputs
    float fact0, fact1;
    {
        int f = 1, c = 1;
#pragma unroll
        for (int j = 1; j < 5; ++j) { c = (m5b0[j] == m5b0[j - 1]) ? c + 1 : 1; f *= c; }
        fact0 = (float)f;
        f = 1; c = 1;
#pragma unroll
        for (int j = 1; j < 5; ++j) { c = (m5b1[j] == m5b1[j - 1]) ? c + 1 : 1; f *= c; }
        fact1 = (float)f;
    }

    // ---- phase 1: h = x[n] @ Wd^T + bd -> D1 = exp(i h / pi) ------------
    float acc[10];
#pragma unroll
    for (int j = 0; j < 10; ++j) acc[j] = xv * wv[j];
#pragma unroll
    for (int off = 32; off > 0; off >>= 1)
#pragma unroll
        for (int j = 0; j < 10; ++j) acc[j] += __shfl_xor(acc[j], off, 64);
    if (lane == 0)
#pragma unroll
        for (int j = 0; j < 10; ++j) sred[j][wid] = acc[j];
    __syncthreads();
    if (tid < 10) {
        float h = bd[tid];
#pragma unroll
        for (int w = 0; w < 16; ++w) h += sred[tid][w];
        float s, c;
        sincosf(h * 0.31830988618379067154f, &s, &c);
        Dsh[tid] = make_float2(c, s);
    }
    __syncthreads();
    // B1 = U1L diag(D1) U1R[:, even]; col-0 threads also seed DP stage 1
    if (tid < 50) {
        const int i = tid / 5, cc = tid % 5, k = 2 * cc;
        float2 a = make_float2(0.f, 0.f);
#pragma unroll
        for (int j = 0; j < 10; ++j) {
            float2 ul = make_float2(U1L[(i * 10 + j) * 2], U1L[(i * 10 + j) * 2 + 1]);
            float2 ur = make_float2(U1R[(j * 10 + k) * 2], U1R[(j * 10 + k) * 2 + 1]);
            float2 t = cxmul(cxmul(ul, Dsh[j]), ur);
            a.x += t.x; a.y += t.y;
        }
        Bsh[tid] = a;
        if (cc == 0) buf1[i] = a;      // stage-1 coeffs = B[:,0]
    }
    __syncthreads();

    // ---- circuit-1 DP ---------------------------------------------------
    if (tid < 55) {
        float2 a = make_float2(0.f, 0.f);
#pragma unroll
        for (int j = 0; j < 2; ++j) a = dp_acc(a, e2[j], buf1, Bsh, 1);
        buf2[tid] = a;
    }
    __syncthreads();
    if (tid < 220) {
        float2 a = make_float2(0.f, 0.f);
#pragma unroll
        for (int j = 0; j < 3; ++j) a = dp_acc(a, e3[j], buf2, Bsh, 2);
        buf1[tid] = a;
    }
    __syncthreads();
    if (tid < 715) {
        float2 a = make_float2(0.f, 0.f);
#pragma unroll
        for (int j = 0; j < 4; ++j) a = dp_acc(a, e4[j], buf1, Bsh, 3);
        buf2[tid] = a;
    }
    __syncthreads();
    if (tid < 252) {
        float2 a = make_float2(0.f, 0.f);
#pragma unroll
        for (int j = 0; j < 5; ++j) a = dp_acc(a, e5a[j], buf2, Bsh, 4);
        p1s[tid] = fmaf(a.x, a.x, a.y * a.y);   // squarefree: prod(mu!) = 1
    } else if (tid < 256) {
        p1s[tid] = 0.f;
    }
    __syncthreads();

    // ---- e1 = (p1/sum) @ mask1 -> D2 -> B2 ------------------------------
    if (tid < 256) {
        float vv = p1s[tid];
#pragma unroll
        for (int off = 32; off > 0; off >>= 1) vv += __shfl_xor(vv, off, 64);
        if (lane == 0) tred[wid] = vv;
    }
    if (tid < 320) {
        const int c = tid / 10, j = tid - c * 10;
        float s = 0.f;
        const int p0 = c * 8, p1e = (p0 + 8 < 252) ? p0 + 8 : 252;
        for (int p = p0; p < p1e; ++p) s = fmaf(p1s[p], mask1[p * 10 + j], s);
        epart[c][j] = s;
    }
    __syncthreads();
    if (tid < 10) {
        const float total = tred[0] + tred[1] + tred[2] + tred[3];
        float e = 0.f;
#pragma unroll
        for (int c = 0; c < 32; ++c) e += epart[c][tid];
        e /= total;
        float s, cc;
        sincosf(e, &s, &cc);
        Dsh[tid] = make_float2(cc, s);
    }
    __syncthreads();
    if (tid < 50) {
        const int i = tid / 5, cc = tid % 5, k = 2 * cc;
        float2 a = make_float2(0.f, 0.f);
#pragma unroll
        for (int j = 0; j < 10; ++j) {
            float2 ul = make_float2(UfL[(i * 10 + j) * 2], UfL[(i * 10 + j) * 2 + 1]);
            float2 ur = make_float2(UfR[(j * 10 + k) * 2], UfR[(j * 10 + k) * 2 + 1]);
            float2 t = cxmul(cxmul(ul, Dsh[j]), ur);
            a.x += t.x; a.y += t.y;
        }
        Bsh[tid] = a;
        if (cc == 0) buf1[i] = a;
    }
    __syncthreads();

    // ---- circuit-2 DP (same edges) --------------------------------------
    if (tid < 55) {
        float2 a = make_float2(0.f, 0.f);
#pragma unroll
        for (int j = 0; j < 2; ++j) a = dp_acc(a, e2[j], buf1, Bsh, 1);
        buf2[tid] = a;
    }
    __syncthreads();
    if (tid < 220) {
        float2 a = make_float2(0.f, 0.f);
#pragma unroll
        for (int j = 0; j < 3; ++j) a = dp_acc(a, e3[j], buf2, Bsh, 2);
        buf1[tid] = a;
    }
    __syncthreads();
    if (tid < 715) {
        float2 a = make_float2(0.f, 0.f);
#pragma unroll
        for (int j = 0; j < 4; ++j) a = dp_acc(a, e4[j], buf1, Bsh, 3);
        buf2[tid] = a;
    }
    __syncthreads();
    float f0 = 0.f, f1 = 0.f;
    {
        float2 a = make_float2(0.f, 0.f);
#pragma unroll
        for (int j = 0; j < 5; ++j) a = dp_acc(a, e5b0[j], buf2, Bsh, 4);
        const float pf = fmaf(a.x, a.x, a.y * a.y) * fact0;   // |coeff|^2 * prod(mu!)
        f0 = fmaf(pf, Wout[tid], f0);
        f1 = fmaf(pf, Wout[2002 + tid], f1);
    }
    if (has_p1) {
        float2 a = make_float2(0.f, 0.f);
#pragma unroll
        for (int j = 0; j < 5; ++j) a = dp_acc(a, e5b1[j], buf2, Bsh, 4);
        const float pf = fmaf(a.x, a.x, a.y * a.y) * fact1;
        f0 = fmaf(pf, Wout[tid + 1024], f0);
        f1 = fmaf(pf, Wout[2002 + tid + 1024], f1);
    }
#pragma unroll
    for (int off = 32; off > 0; off >>= 1) {
        f0 += __shfl_xor(f0, off, 64);
        f1 += __shfl_xor(f1, off, 64);
    }
    if (lane == 0) { fred[wid][0] = f0; fred[wid][1] = f1; }
    __syncthreads();
    if (tid < 2) {
        float a = bout[tid];
#pragma unroll
        for (int w = 0; w < 16; ++w) a += fred[w][tid];
        out[n * 2 + tid] = a;
    }
}

extern "C" void kernel_launch(void* const* d_in, const int* in_sizes, int n_in,
                              void* d_out, int out_size, void* d_ws, size_t ws_size,
                              hipStream_t stream) {
    const float* x     = (const float*)d_in[0];
    const float* Wd    = (const float*)d_in[1];
    const float* bd    = (const float*)d_in[2];
    const float* U1L   = (const float*)d_in[3];
    const float* U1R   = (const float*)d_in[4];
    const float* UfL   = (const float*)d_in[5];
    const float* UfR   = (const float*)d_in[6];
    const float* Wout  = (const float*)d_in[7];
    const float* bout  = (const float*)d_in[8];
    const float* mask1 = (const float*)d_in[9];
    const float* norm2 = (const float*)d_in[10];
    const int*   rows1 = (const int*)d_in[11];
    const int*   rows2 = (const int*)d_in[12];
    float* out = (float*)d_out;

    hipLaunchKernelGGL(k_fused, dim3(256), dim3(1024), 0, stream,
                       x, Wd, bd, U1L, U1R, UfL, UfR, Wout, bout,
                       mask1, norm2, rows1, rows2, out);
}

// Round 8
// 14.681 us; speedup vs baseline: 1.3838x; 1.1470x over previous
//
#include <hip/hip_runtime.h>
#include <hip/hip_bf16.h>

// Fully-fused quantum photonic classifier via polynomial-coefficient DP.
// perm(B[rows mu]) / prod(mu!) = coeff of x^mu in prod_c (sum_m x_m B[m][c]).
// One block per sample (256 x 1024). DP stages over multiset degrees
// 1(10) -> 2(55) -> 3(220) -> 4(715) -> 5(2002).
// R8 vs R7: (a) phase-1 matvec = wave-per-mode (6 shuffles instead of 60/thread),
// (b) e1 = wave-per-mode fused mask+total reduce (removes 2 barriers + serial
// loops), (c) edge builds deferred into DP barrier gaps, (d) fast __sincosf.

__device__ __forceinline__ float2 cxmul(float2 a, float2 b) {
    float2 r;
    r.x = fmaf(a.x, b.x, -(a.y * b.y));
    r.y = fmaf(a.x, b.y, a.y * b.x);
    return r;
}

// exact C(c,k) for 0 <= c <= 14, 0 <= k <= 5. Products auto-zero for c < k.
__device__ __forceinline__ int Crt(int c, int k) {
    switch (k) {
        case 0:  return 1;
        case 1:  return c;
        case 2:  return (int)((unsigned)(c * (c - 1)) >> 1);
        case 3:  return (int)((unsigned)(c * (c - 1) * (c - 2)) / 6u);
        case 4:  return (int)((unsigned)(c * (c - 1) * (c - 2) * (c - 3)) / 24u);
        default: return (int)((unsigned)(c * (c - 1) * (c - 2) * (c - 3) * (c - 4)) / 120u);
    }
}

// colex unrank of a degree-D multiset over modes 0..9 (branchless).
template<int D>
__device__ __forceinline__ void unrank_ms(int R, int (&m)[D]) {
#pragma unroll
    for (int i = D - 1; i >= 0; --i) {
        int c = i;
#pragma unroll
        for (int v = 1; v <= 9; ++v)
            c += (Crt(i + v, i + 1) <= R) ? 1 : 0;
        R -= Crt(c, i + 1);
        m[i] = c - i;
    }
}

// For sorted multiset m[0..D-1]: edge j = (rank of multiset minus m[j],
// mode m[j]), valid only at first occurrence of each distinct value.
template<int D>
__device__ __forceinline__ void build_edges(const int (&m)[D], unsigned (&e)[D]) {
    int c[D];
#pragma unroll
    for (int i = 0; i < D; ++i) c[i] = m[i] + i;
    int P[D];
    P[0] = 0;
#pragma unroll
    for (int j = 1; j < D; ++j) P[j] = P[j - 1] + Crt(c[j - 1], j);
    int S[D];
    S[D - 1] = 0;
#pragma unroll
    for (int j = D - 2; j >= 0; --j) S[j] = S[j + 1] + Crt(c[j + 1] - 1, j + 1);
#pragma unroll
    for (int j = 0; j < D; ++j) {
        bool valid = (j == 0) || (m[j] != m[j - 1]);
        unsigned edge = (((unsigned)(P[j] + S[j])) << 4) | (unsigned)m[j] | 0x80000000u;
        e[j] = valid ? edge : 0u;
    }
}

// acc += B[mode][col] * parent_coeff   (complex, 4 fma)
__device__ __forceinline__ float2 dp_acc(float2 acc, unsigned e, const float2* pbuf,
                                         const float2* B, int col) {
    if (e & 0x80000000u) {
        float2 p = pbuf[(e >> 4) & 0x3FFu];
        float2 b = B[(e & 15u) * 5 + col];
        acc.x = fmaf(b.x, p.x, acc.x);
        acc.x = fmaf(-b.y, p.y, acc.x);
        acc.y = fmaf(b.x, p.y, acc.y);
        acc.y = fmaf(b.y, p.x, acc.y);
    }
    return acc;
}

__global__ __launch_bounds__(1024) void k_fused(
    const float* __restrict__ x, const float* __restrict__ Wd, const float* __restrict__ bd,
    const float* __restrict__ U1L, const float* __restrict__ U1R,
    const float* __restrict__ UfL, const float* __restrict__ UfR,
    const float* __restrict__ Wout, const float* __restrict__ bout,
    const float* __restrict__ mask1, const float* __restrict__ norm2,
    const int* __restrict__ rows1, const int* __restrict__ rows2,
    float* __restrict__ out)
{
    const int n    = blockIdx.x;
    const int tid  = threadIdx.x;
    const int lane = tid & 63;
    const int wid  = tid >> 6;   // 16 waves

    __shared__ float2 Bsh[50];        // current circuit matrix (10 modes x 5 cols)
    __shared__ float2 buf1[220];      // DP stages 1,3
    __shared__ float2 buf2[715];      // DP stages 2,4
    __shared__ float  p1s[252];
    __shared__ float2 Dsh[10];
    __shared__ float  fred[16][2];

    // ---- early-issue global loads of row multisets ----------------------
    int m5a[5];
#pragma unroll
    for (int j = 0; j < 5; ++j) m5a[j] = 0;
    if (tid < 252) {
#pragma unroll
        for (int j = 0; j < 5; ++j) m5a[j] = rows1[tid * 5 + j];
    }
    int m5b0[5];                       // p0 = tid (< 2002 always)
#pragma unroll
    for (int j = 0; j < 5; ++j) m5b0[j] = rows2[tid * 5 + j];
    int m5b1[5];                       // p1 = tid + 1024
#pragma unroll
    for (int j = 0; j < 5; ++j) m5b1[j] = 0;
    const bool has_p1 = (tid + 1024) < 2002;
    if (has_p1) {
#pragma unroll
        for (int j = 0; j < 5; ++j) m5b1[j] = rows2[(tid + 1024) * 5 + j];
    }

    // ---- phase 1: wave j computes h[j] = x[n]·Wd[j,:] + bd[j] -> D1 -----
    if (wid < 10) {
        const float* xr = x + n * 784;
        const float* wr = Wd + wid * 784;
        float s = 0.f;
#pragma unroll
        for (int t = 0; t < 12; ++t) {
            const int k = lane + t * 64;
            s = fmaf(xr[k], wr[k], s);
        }
        if (lane < 16) {
            const int k = lane + 768;
            s = fmaf(xr[k], wr[k], s);
        }
#pragma unroll
        for (int off = 32; off > 0; off >>= 1) s += __shfl_xor(s, off, 64);
        if (lane == 0) {
            float h = s + bd[wid];
            float sn, cs;
            __sincosf(h * 0.31830988618379067154f, &sn, &cs);   // h / pi
            Dsh[wid] = make_float2(cs, sn);
        }
    }
    // cheap stage-2 edges while waiting
    unsigned e2[2];
#pragma unroll
    for (int j = 0; j < 2; ++j) e2[j] = 0u;
    if (tid < 55)  { int m[2]; unrank_ms<2>(tid, m); build_edges<2>(m, e2); }
    __syncthreads();

    // ---- B1 = U1L diag(D1) U1R[:, even]; col-0 seeds DP stage 1 ---------
    if (tid < 50) {
        const int i = tid / 5, cc = tid % 5, k = 2 * cc;
        float2 a = make_float2(0.f, 0.f);
#pragma unroll
        for (int j = 0; j < 10; ++j) {
            float2 ul = make_float2(U1L[(i * 10 + j) * 2], U1L[(i * 10 + j) * 2 + 1]);
            float2 ur = make_float2(U1R[(j * 10 + k) * 2], U1R[(j * 10 + k) * 2 + 1]);
            float2 t = cxmul(cxmul(ul, Dsh[j]), ur);
            a.x += t.x; a.y += t.y;
        }
        Bsh[tid] = a;
        if (cc == 0) buf1[i] = a;      // stage-1 coeffs = B[:,0]
    }
    __syncthreads();

    // ---- circuit-1 DP (edge builds deferred into barrier gaps) ----------
    if (tid < 55) {
        float2 a = make_float2(0.f, 0.f);
#pragma unroll
        for (int j = 0; j < 2; ++j) a = dp_acc(a, e2[j], buf1, Bsh, 1);
        buf2[tid] = a;
    }
    unsigned e3[3];
#pragma unroll
    for (int j = 0; j < 3; ++j) e3[j] = 0u;
    if (tid < 220) { int m[3]; unrank_ms<3>(tid, m); build_edges<3>(m, e3); }
    __syncthreads();
    if (tid < 220) {
        float2 a = make_float2(0.f, 0.f);
#pragma unroll
        for (int j = 0; j < 3; ++j) a = dp_acc(a, e3[j], buf2, Bsh, 2);
        buf1[tid] = a;
    }
    unsigned e4[4];
#pragma unroll
    for (int j = 0; j < 4; ++j) e4[j] = 0u;
    if (tid < 715) { int m[4]; unrank_ms<4>(tid, m); build_edges<4>(m, e4); }
    __syncthreads();
    if (tid < 715) {
        float2 a = make_float2(0.f, 0.f);
#pragma unroll
        for (int j = 0; j < 4; ++j) a = dp_acc(a, e4[j], buf1, Bsh, 3);
        buf2[tid] = a;
    }
    unsigned e5a[5], e5b0[5], e5b1[5];
#pragma unroll
    for (int j = 0; j < 5; ++j) { e5a[j] = 0u; e5b1[j] = 0u; }
    if (tid < 252) { build_edges<5>(m5a, e5a); }
    build_edges<5>(m5b0, e5b0);
    if (has_p1) { build_edges<5>(m5b1, e5b1); }
    float fact0, fact1;
    {
        int f = 1, c = 1;
#pragma unroll
        for (int j = 1; j < 5; ++j) { c = (m5b0[j] == m5b0[j - 1]) ? c + 1 : 1; f *= c; }
        fact0 = (float)f;
        f = 1; c = 1;
#pragma unroll
        for (int j = 1; j < 5; ++j) { c = (m5b1[j] == m5b1[j - 1]) ? c + 1 : 1; f *= c; }
        fact1 = (float)f;
    }
    __syncthreads();
    if (tid < 252) {
        float2 a = make_float2(0.f, 0.f);
#pragma unroll
        for (int j = 0; j < 5; ++j) a = dp_acc(a, e5a[j], buf2, Bsh, 4);
        p1s[tid] = fmaf(a.x, a.x, a.y * a.y);   // squarefree: prod(mu!) = 1
    }
    __syncthreads();

    // ---- e1: wave j computes (p1·mask1[:,j]) / sum(p1) -> D2 ------------
    if (wid < 10) {
        float sm = 0.f, st = 0.f;
        for (int p = lane; p < 252; p += 64) {
            const float pv = p1s[p];
            sm = fmaf(pv, mask1[p * 10 + wid], sm);
            st += pv;
        }
#pragma unroll
        for (int off = 32; off > 0; off >>= 1) {
            sm += __shfl_xor(sm, off, 64);
            st += __shfl_xor(st, off, 64);
        }
        if (lane == 0) {
            float e = sm / st;
            float sn, cs;
            __sincosf(e, &sn, &cs);
            Dsh[wid] = make_float2(cs, sn);
        }
    }
    __syncthreads();
    if (tid < 50) {
        const int i = tid / 5, cc = tid % 5, k = 2 * cc;
        float2 a = make_float2(0.f, 0.f);
#pragma unroll
        for (int j = 0; j < 10; ++j) {
            float2 ul = make_float2(UfL[(i * 10 + j) * 2], UfL[(i * 10 + j) * 2 + 1]);
            float2 ur = make_float2(UfR[(j * 10 + k) * 2], UfR[(j * 10 + k) * 2 + 1]);
            float2 t = cxmul(cxmul(ul, Dsh[j]), ur);
            a.x += t.x; a.y += t.y;
        }
        Bsh[tid] = a;      // overwrite with B2 (all B1 consumers done)
        if (cc == 0) buf1[i] = a;
    }
    __syncthreads();

    // ---- circuit-2 DP (same register-resident edges) --------------------
    if (tid < 55) {
        float2 a = make_float2(0.f, 0.f);
#pragma unroll
        for (int j = 0; j < 2; ++j) a = dp_acc(a, e2[j], buf1, Bsh, 1);
        buf2[tid] = a;
    }
    __syncthreads();
    if (tid < 220) {
        float2 a = make_float2(0.f, 0.f);
#pragma unroll
        for (int j = 0; j < 3; ++j) a = dp_acc(a, e3[j], buf2, Bsh, 2);
        buf1[tid] = a;
    }
    __syncthreads();
    if (tid < 715) {
        float2 a = make_float2(0.f, 0.f);
#pragma unroll
        for (int j = 0; j < 4; ++j) a = dp_acc(a, e4[j], buf1, Bsh, 3);
        buf2[tid] = a;
    }
    __syncthreads();
    float f0 = 0.f, f1 = 0.f;
    {
        float2 a = make_float2(0.f, 0.f);
#pragma unroll
        for (int j = 0; j < 5; ++j) a = dp_acc(a, e5b0[j], buf2, Bsh, 4);
        const float pf = fmaf(a.x, a.x, a.y * a.y) * fact0;   // |coeff|^2 * prod(mu!)
        f0 = fmaf(pf, Wout[tid], f0);
        f1 = fmaf(pf, Wout[2002 + tid], f1);
    }
    if (has_p1) {
        float2 a = make_float2(0.f, 0.f);
#pragma unroll
        for (int j = 0; j < 5; ++j) a = dp_acc(a, e5b1[j], buf2, Bsh, 4);
        const float pf = fmaf(a.x, a.x, a.y * a.y) * fact1;
        f0 = fmaf(pf, Wout[tid + 1024], f0);
        f1 = fmaf(pf, Wout[2002 + tid + 1024], f1);
    }
#pragma unroll
    for (int off = 32; off > 0; off >>= 1) {
        f0 += __shfl_xor(f0, off, 64);
        f1 += __shfl_xor(f1, off, 64);
    }
    if (lane == 0) { fred[wid][0] = f0; fred[wid][1] = f1; }
    __syncthreads();
    if (tid < 2) {
        float a = bout[tid];
#pragma unroll
        for (int w = 0; w < 16; ++w) a += fred[w][tid];
        out[n * 2 + tid] = a;
    }
}

extern "C" void kernel_launch(void* const* d_in, const int* in_sizes, int n_in,
                              void* d_out, int out_size, void* d_ws, size_t ws_size,
                              hipStream_t stream) {
    const float* x     = (const float*)d_in[0];
    const float* Wd    = (const float*)d_in[1];
    const float* bd    = (const float*)d_in[2];
    const float* U1L   = (const float*)d_in[3];
    const float* U1R   = (const float*)d_in[4];
    const float* UfL   = (const float*)d_in[5];
    const float* UfR   = (const float*)d_in[6];
    const float* Wout  = (const float*)d_in[7];
    const float* bout  = (const float*)d_in[8];
    const float* mask1 = (const float*)d_in[9];
    const float* norm2 = (const float*)d_in[10];
    const int*   rows1 = (const int*)d_in[11];
    const int*   rows2 = (const int*)d_in[12];
    float* out = (float*)d_out;

    hipLaunchKernelGGL(k_fused, dim3(256), dim3(1024), 0, stream,
                       x, Wd, bd, U1L, U1R, UfL, UfR, Wout, bout,
                       mask1, norm2, rows1, rows2, out);
}